// Round 10
// baseline (152.179 us; speedup 1.0000x reference)
//
#include <hip/hip_runtime.h>
#include <hip/hip_bf16.h>

#define T_DIM 2048
#define N_DIM 128
#define K_DIM 256
#define C_DIM 40
#define SEG 256
#define SEGLEN 8      // T_DIM / SEG
#define GRP 8
#define SEGPERGRP 32  // SEG / GRP

typedef __attribute__((ext_vector_type(8))) short bf16x8;
typedef __attribute__((ext_vector_type(4))) float f32x4v;

__device__ __forceinline__ unsigned pack_bf16(float a, float b) {
    union { float f; unsigned u; } ua, ub;
    ua.f = a; ub.f = b;
    unsigned ra = (ua.u + 0x7FFFu + ((ua.u >> 16) & 1u)) >> 16;
    unsigned rb = (ub.u + 0x7FFFu + ((ub.u >> 16) & 1u)) >> 16;
    return (ra & 0xFFFFu) | (rb << 16);
}

// hardware packed f32->bf16 (RNE)
__device__ __forceinline__ unsigned cvt_pk(float a, float b) {
    unsigned r;
    asm("v_cvt_pk_bf16_f32 %0, %1, %2" : "=v"(r) : "v"(a), "v"(b));
    return r;
}

__device__ __forceinline__ float bf_lo(unsigned u) {
    union { unsigned x; float f; } v; v.x = u << 16; return v.f;
}
__device__ __forceinline__ float bf_hi(unsigned u) {
    union { unsigned x; float f; } v; v.x = u & 0xFFFF0000u; return v.f;
}

__device__ __forceinline__ float fast_tanh(float v) {
    float e = __expf(2.f * v);
    return 1.f - 2.f / (e + 1.f);
}

// ---------------- Phase 1: y = 5*tanh(x W^T + b), y stored BF16 ------------
// REG-STAGED: x via global_load_dwordx4 -> VGPR (rA/rB, 2-deep prefetch) ->
// ds_write -> ds_read. NO global_load_lds, NO inline-asm waits, NO barriers.
// Per-wave private dbuf 2 x 4KB (16 rows x 64 k-f32 per phase, 4 phases/tile).
// Compiler emits counted vmcnt/lgkmcnt from register deps. W in registers.
__global__ __launch_bounds__(256, 2) void k_gemm_tanh(
    const float* __restrict__ x, const float* __restrict__ W,
    const float* __restrict__ b, unsigned* __restrict__ ybf)
{
    __shared__ __align__(16) float shX[4][2][16][64];   // per-wave 2 bufs x 4KB

    const int tid = threadIdx.x;
    const int lane = tid & 63;
    const int wave = tid >> 6;
    const int lr = lane & 15;      // x-row within tile / MFMA B-col
    const int kg = lane >> 4;      // k-chunk group 0..3
    const int bid = blockIdx.x;
    const int sbid = (bid & 7) * 64 + (bid >> 3);   // XCD chunk swizzle
    const int gw = sbid * 4 + wave;                 // 0..2047
    const int ldr = lane >> 4;          // row sub-index for loads (0..3)
    const int ldc = (lane & 15) * 16;   // byte col within 256B phase window
    const int sw = (lr & 7) << 4;       // read-side XOR swizzle

    // ---- W fragments in registers ----
    bf16x8 wf[3][8];
    #pragma unroll
    for (int cb = 0; cb < 3; ++cb) {
        #pragma unroll
        for (int kk = 0; kk < 8; ++kk) {
            int rowc = cb * 16 + lr;
            float4 w0 = {0.f, 0.f, 0.f, 0.f}, w1 = {0.f, 0.f, 0.f, 0.f};
            if (rowc < C_DIM) {
                const float* wp = W + rowc * K_DIM + kg * 8 + kk * 32;
                w0 = *reinterpret_cast<const float4*>(wp);
                w1 = *reinterpret_cast<const float4*>(wp + 4);
            }
            union { bf16x8 v; unsigned u[4]; } uw;
            uw.u[0] = pack_bf16(w0.x, w0.y);
            uw.u[1] = pack_bf16(w0.z, w0.w);
            uw.u[2] = pack_bf16(w1.x, w1.y);
            uw.u[3] = pack_bf16(w1.z, w1.w);
            wf[cb][kk] = uw.v;
        }
    }

    float4 bia0 = *reinterpret_cast<const float4*>(b + kg * 4);
    float4 bia1 = *reinterpret_cast<const float4*>(b + 16 + kg * 4);
    float4 bia2 = {0.f, 0.f, 0.f, 0.f};
    if (kg < 2) bia2 = *reinterpret_cast<const float4*>(b + 32 + kg * 4);

    const char* xb = reinterpret_cast<const char*>(x);
    char* lds0 = reinterpret_cast<char*>(&shX[wave][0][0][0]);
    char* lds1 = reinterpret_cast<char*>(&shX[wave][1][0][0]);

    float4 rA[4], rB[4];
    f32x4v acc0, acc1, acc2;

// load phase P (static) of tile TT (runtime) into regset R: 4x dwordx4
#define LOADP(R, TT, P)                                                        \
    do {                                                                       \
        const char* base_ = xb + ((size_t)(TT) * 2048 + gw) * 16384 + (P) * 256; \
        _Pragma("unroll")                                                      \
        for (int j = 0; j < 4; ++j)                                            \
            R[j] = *reinterpret_cast<const float4*>(base_ + (4 * j + ldr) * 1024 + ldc); \
    } while (0)

// ds_write regset R into buffer LB (swizzled)
#define WRITEP(R, LB)                                                          \
    do {                                                                       \
        _Pragma("unroll")                                                      \
        for (int j = 0; j < 4; ++j) {                                          \
            int r_ = 4 * j + ldr;                                              \
            *reinterpret_cast<float4*>((LB) + r_ * 256 + (ldc ^ ((r_ & 7) << 4))) = R[j]; \
        }                                                                      \
    } while (0)

// consume buffer LB as phase P (static): 2 k-steps x (2 ds_read + cvt + 3 MFMA)
#define COMPUTEP(LB, P)                                                        \
    do {                                                                       \
        _Pragma("unroll")                                                      \
        for (int ks = 0; ks < 2; ++ks) {                                       \
            int c_ = ks * 128 + kg * 32;                                       \
            float4 d0 = *reinterpret_cast<const float4*>((LB) + lr * 256 + (c_ ^ sw));        \
            float4 d1 = *reinterpret_cast<const float4*>((LB) + lr * 256 + ((c_ + 16) ^ sw)); \
            union { bf16x8 v; unsigned u[4]; } xf;                             \
            xf.u[0] = cvt_pk(d0.x, d0.y);                                      \
            xf.u[1] = cvt_pk(d0.z, d0.w);                                      \
            xf.u[2] = cvt_pk(d1.x, d1.y);                                      \
            xf.u[3] = cvt_pk(d1.z, d1.w);                                      \
            acc0 = __builtin_amdgcn_mfma_f32_16x16x32_bf16(wf[0][(P) * 2 + ks], xf.v, acc0, 0, 0, 0); \
            acc1 = __builtin_amdgcn_mfma_f32_16x16x32_bf16(wf[1][(P) * 2 + ks], xf.v, acc1, 0, 0, 0); \
            acc2 = __builtin_amdgcn_mfma_f32_16x16x32_bf16(wf[2][(P) * 2 + ks], xf.v, acc2, 0, 0, 0); \
        }                                                                      \
    } while (0)

    // prologue: q0 -> rA -> L0 ; q1 -> rB (in flight)
    LOADP(rA, 0, 0);
    LOADP(rB, 0, 1);
    WRITEP(rA, lds0);

    for (int tt = 0; tt < 8; ++tt) {
        acc0 = (f32x4v){0.f, 0.f, 0.f, 0.f};
        acc1 = (f32x4v){0.f, 0.f, 0.f, 0.f};
        acc2 = (f32x4v){0.f, 0.f, 0.f, 0.f};

        LOADP(rA, tt, 2);                 // q = 4tt+2
        WRITEP(rB, lds1);                 // q = 4tt+1 -> L1
        COMPUTEP(lds0, 0);                // phase 0 (q = 4tt)

        LOADP(rB, tt, 3);                 // q = 4tt+3
        WRITEP(rA, lds0);                 // q = 4tt+2 -> L0
        COMPUTEP(lds1, 1);                // phase 1

        if (tt < 7) LOADP(rA, tt + 1, 0); // q = 4tt+4
        WRITEP(rB, lds1);                 // q = 4tt+3 -> L1
        COMPUTEP(lds0, 2);                // phase 2

        if (tt < 7) LOADP(rB, tt + 1, 1); // q = 4tt+5
        if (tt < 7) WRITEP(rA, lds0);     // q = 4tt+4 -> L0
        COMPUTEP(lds1, 3);                // phase 3

        // ---- epilogue: bias + tanh + bf16 store ----
        size_t row = ((size_t)tt * 2048 + gw) * 16 + lr;
        unsigned* yr = ybf + row * 20;    // 40 bf16 = 20 u32 per row
        float o00 = 5.f * fast_tanh(acc0[0] + bia0.x);
        float o01 = 5.f * fast_tanh(acc0[1] + bia0.y);
        float o02 = 5.f * fast_tanh(acc0[2] + bia0.z);
        float o03 = 5.f * fast_tanh(acc0[3] + bia0.w);
        float o10 = 5.f * fast_tanh(acc1[0] + bia1.x);
        float o11 = 5.f * fast_tanh(acc1[1] + bia1.y);
        float o12 = 5.f * fast_tanh(acc1[2] + bia1.z);
        float o13 = 5.f * fast_tanh(acc1[3] + bia1.w);
        uint2 p0, p1;
        p0.x = cvt_pk(o00, o01); p0.y = cvt_pk(o02, o03);
        p1.x = cvt_pk(o10, o11); p1.y = cvt_pk(o12, o13);
        *reinterpret_cast<uint2*>(yr + kg * 2) = p0;
        *reinterpret_cast<uint2*>(yr + 8 + kg * 2) = p1;
        if (kg < 2) {
            float o20 = 5.f * fast_tanh(acc2[0] + bia2.x);
            float o21 = 5.f * fast_tanh(acc2[1] + bia2.y);
            float o22 = 5.f * fast_tanh(acc2[2] + bia2.z);
            float o23 = 5.f * fast_tanh(acc2[3] + bia2.w);
            uint2 p2;
            p2.x = cvt_pk(o20, o21); p2.y = cvt_pk(o22, o23);
            *reinterpret_cast<uint2*>(yr + 16 + kg * 2) = p2;
        }
    }
#undef LOADP
#undef WRITEP
#undef COMPUTEP
}

// ---------------- Phase 2a: per-segment 8x8 transition matrices ------------
__global__ __launch_bounds__(128) void k_seg(
    const unsigned* __restrict__ ybf, float* __restrict__ segv, float* __restrict__ segl)
{
    int tid = blockIdx.x * 128 + threadIdx.x;   // 32768 total
    int n = tid & 127;
    int s = tid >> 7;

    float P[8][8];
    #pragma unroll
    for (int j = 0; j < 8; ++j)
        #pragma unroll
        for (int c = 0; c < 8; ++c) P[j][c] = (j == c) ? 1.f : 0.f;

    for (int st = 0; st < SEGLEN; ++st) {
        int t = s * SEGLEN + st;
        const unsigned* yr = ybf + ((size_t)t * N_DIM + n) * 20;
        float e[40];
        #pragma unroll
        for (int i = 0; i < 5; ++i) {
            uint4 w = reinterpret_cast<const uint4*>(yr)[i];
            e[i * 8 + 0] = __expf(bf_lo(w.x));
            e[i * 8 + 1] = __expf(bf_hi(w.x));
            e[i * 8 + 2] = __expf(bf_lo(w.y));
            e[i * 8 + 3] = __expf(bf_hi(w.y));
            e[i * 8 + 4] = __expf(bf_lo(w.z));
            e[i * 8 + 5] = __expf(bf_hi(w.z));
            e[i * 8 + 6] = __expf(bf_lo(w.w));
            e[i * 8 + 7] = __expf(bf_hi(w.w));
        }
        #pragma unroll
        for (int c = 0; c < 8; ++c) {
            float np[8];
            #pragma unroll
            for (int j = 0; j < 4; ++j) {       // flip: all 8 sources
                float a = 0.f;
                #pragma unroll
                for (int i = 0; i < 8; ++i) a += P[i][c] * e[j * 8 + i];
                np[j] = a;
            }
            #pragma unroll
            for (int j = 0; j < 4; ++j)         // flop: 2 sources
                np[4 + j] = P[j][c] * e[32 + j] + P[4 + j][c] * e[36 + j];
            #pragma unroll
            for (int j = 0; j < 8; ++j) P[j][c] = np[j];
        }
    }
    #pragma unroll
    for (int c = 0; c < 8; ++c) {
        float sum = 0.f;
        #pragma unroll
        for (int j = 0; j < 8; ++j) sum += P[j][c];
        float inv = 1.f / sum;
        #pragma unroll
        for (int j = 0; j < 8; ++j)
            segv[(((size_t)s * 8 + c) * 8 + j) * N_DIM + n] = P[j][c] * inv;
        segl[((size_t)s * 8 + c) * N_DIM + n] = __logf(sum);
    }
}

// ---------------- Phase 2b: combine 32 segments per group ------------------
__global__ __launch_bounds__(128) void k_grp(
    const float* __restrict__ segv, const float* __restrict__ segl,
    float* __restrict__ grpv, float* __restrict__ grpl)
{
    int tid = blockIdx.x * 128 + threadIdx.x;  // 8192 total (64 blocks)
    int n = tid & 127;
    int cc = (tid >> 7) & 7;
    int g = tid >> 10;

    float u[8];
    #pragma unroll
    for (int i = 0; i < 8; ++i) u[i] = (i == cc) ? 1.f : 0.f;
    float logacc = 0.f;

    for (int s = g * SEGPERGRP; s < (g + 1) * SEGPERGRP; ++s) {
        float l[8];
        #pragma unroll
        for (int i = 0; i < 8; ++i) l[i] = segl[((size_t)s * 8 + i) * N_DIM + n];
        float m = l[0];
        #pragma unroll
        for (int i = 1; i < 8; ++i) m = fmaxf(m, l[i]);
        float nu[8] = {0.f, 0.f, 0.f, 0.f, 0.f, 0.f, 0.f, 0.f};
        #pragma unroll
        for (int i = 0; i < 8; ++i) {
            float wi = u[i] * __expf(l[i] - m);
            #pragma unroll
            for (int j = 0; j < 8; ++j)
                nu[j] += wi * segv[(((size_t)s * 8 + i) * 8 + j) * N_DIM + n];
        }
        float sum = 0.f;
        #pragma unroll
        for (int j = 0; j < 8; ++j) sum += nu[j];
        float inv = 1.f / sum;
        #pragma unroll
        for (int j = 0; j < 8; ++j) u[j] = nu[j] * inv;
        logacc += m + __logf(sum);
    }
    #pragma unroll
    for (int j = 0; j < 8; ++j)
        grpv[(((size_t)g * 8 + cc) * 8 + j) * N_DIM + n] = u[j];
    grpl[((size_t)g * 8 + cc) * N_DIM + n] = logacc;
}

// ---------------- Phase 2c: fold 8 groups into logZ/T ----------------------
__global__ void k_fin(const float* __restrict__ grpv, const float* __restrict__ grpl,
                      float* __restrict__ lz)
{
    int n = threadIdx.x;  // 128
    float p[8] = {0.25f, 0.25f, 0.25f, 0.25f, 0.f, 0.f, 0.f, 0.f};
    float logZ = 1.3862943611198906f;  // log(4)

    for (int g = 0; g < GRP; ++g) {
        float l[8];
        #pragma unroll
        for (int i = 0; i < 8; ++i) l[i] = grpl[((size_t)g * 8 + i) * N_DIM + n];
        float m = l[0];
        #pragma unroll
        for (int i = 1; i < 8; ++i) m = fmaxf(m, l[i]);
        float nu[8] = {0.f, 0.f, 0.f, 0.f, 0.f, 0.f, 0.f, 0.f};
        #pragma unroll
        for (int i = 0; i < 8; ++i) {
            float wi = p[i] * __expf(l[i] - m);
            #pragma unroll
            for (int j = 0; j < 8; ++j)
                nu[j] += wi * grpv[(((size_t)g * 8 + i) * 8 + j) * N_DIM + n];
        }
        float sum = 0.f;
        #pragma unroll
        for (int j = 0; j < 8; ++j) sum += nu[j];
        float inv = 1.f / sum;
        #pragma unroll
        for (int j = 0; j < 8; ++j) p[j] = nu[j] * inv;
        logZ += m + __logf(sum);
    }
    lz[n] = logZ * (1.f / (float)T_DIM);
}

// ---------------- Phase 3: out = y(bf16) - logZ[n]/T -----------------------
__global__ __launch_bounds__(256) void k_sub(const unsigned* __restrict__ ybf,
                                             const float* __restrict__ lz,
                                             float* __restrict__ out)
{
    int i = blockIdx.x * 256 + threadIdx.x;   // float4-out index; 2621440 total
    int n = (i / 10) & 127;
    float d = lz[n];
    uint2 w = *reinterpret_cast<const uint2*>(ybf + 2 * (size_t)i);
    float4 v;
    v.x = bf_lo(w.x) - d;
    v.y = bf_hi(w.x) - d;
    v.z = bf_lo(w.y) - d;
    v.w = bf_hi(w.y) - d;
    reinterpret_cast<float4*>(out)[i] = v;
}

extern "C" void kernel_launch(void* const* d_in, const int* in_sizes, int n_in,
                              void* d_out, int out_size, void* d_ws, size_t ws_size,
                              hipStream_t stream) {
    const float* x = (const float*)d_in[0];
    const float* W = (const float*)d_in[1];
    const float* b = (const float*)d_in[2];
    float* out = (float*)d_out;
    float* ws = (float*)d_ws;

    unsigned* ybf = (unsigned*)ws;     // T*N*20 u32  (20MB)
    float* segv = ws + 5242880;        // SEG*8*8*128 = 2,097,152 f32
    float* segl = ws + 7340032;        // SEG*8*128   =   262,144 f32
    float* grpv = ws + 7602176;        // GRP*8*8*128 =    65,536 f32
    float* grpl = ws + 7667712;        // GRP*8*128   =     8,192 f32
    float* lz   = ws + 7675904;        // 128 f32     (total ~30.7 MB)

    k_gemm_tanh<<<512, 256, 0, stream>>>(x, W, b, ybf);
    k_seg<<<256, 128, 0, stream>>>(ybf, segv, segl);
    k_grp<<<64, 128, 0, stream>>>(segv, segl, grpv, grpl);
    k_fin<<<1, 128, 0, stream>>>(grpv, grpl, lz);
    k_sub<<<10240, 256, 0, stream>>>(ybf, lz, out);
}

// Round 11
// 137.768 us; speedup vs baseline: 1.1046x; 1.1046x over previous
//
#include <hip/hip_runtime.h>
#include <hip/hip_bf16.h>

#define T_DIM 2048
#define N_DIM 128
#define K_DIM 256
#define C_DIM 40
#define SEG 256
#define SEGLEN 8      // T_DIM / SEG
#define GRP 8
#define SEGPERGRP 32  // SEG / GRP

typedef __attribute__((ext_vector_type(8))) short bf16x8;
typedef __attribute__((ext_vector_type(4))) float f32x4v;

__device__ __forceinline__ unsigned pack_bf16(float a, float b) {
    union { float f; unsigned u; } ua, ub;
    ua.f = a; ub.f = b;
    unsigned ra = (ua.u + 0x7FFFu + ((ua.u >> 16) & 1u)) >> 16;
    unsigned rb = (ub.u + 0x7FFFu + ((ub.u >> 16) & 1u)) >> 16;
    return (ra & 0xFFFFu) | (rb << 16);
}

// hardware packed f32->bf16 (RNE)
__device__ __forceinline__ unsigned cvt_pk(float a, float b) {
    unsigned r;
    asm("v_cvt_pk_bf16_f32 %0, %1, %2" : "=v"(r) : "v"(a), "v"(b));
    return r;
}

__device__ __forceinline__ float bf_lo(unsigned u) {
    union { unsigned x; float f; } v; v.x = u << 16; return v.f;
}
__device__ __forceinline__ float bf_hi(unsigned u) {
    union { unsigned x; float f; } v; v.x = u & 0xFFFF0000u; return v.f;
}

__device__ __forceinline__ float fast_tanh(float v) {
    float e = __expf(2.f * v);
    return 1.f - 2.f / (e + 1.f);
}

// ---------------- Phase 1: y = 5*tanh(x W^T + b), y stored BF16 ------------
// IDENTICAL to round-9 kernel EXCEPT: the x-stream global_load_lds carries
// aux=2 (CPol NT, non-temporal) so the 256MB single-use x stream does NOT
// allocate into L2/L3. Hypothesis: cache-allocation/evict thrash (x stream =
// 1.0x L3 capacity, 64x per-XCD L2) is the ~3TB/s governor, not DRAM.
__global__ __launch_bounds__(256, 2) void k_gemm_tanh(
    const float* __restrict__ x, const float* __restrict__ W,
    const float* __restrict__ b, unsigned* __restrict__ ybf)
{
    __shared__ __align__(16) float shX[4][2][16][128];  // per-wave dbuf, 8KB each

    const int tid = threadIdx.x;
    const int lane = tid & 63;
    const int wave = tid >> 6;
    const int lr = lane & 15;      // x-row within tile / W-row within c-block
    const int kg = lane >> 4;      // k-chunk group 0..3
    const int bid = blockIdx.x;
    const int sbid = (bid & 7) * 64 + (bid >> 3);   // XCD chunk swizzle
    const int gw = sbid * 4 + wave;                 // 0..2047

    // ---- preload W fragments into registers (one-time, L2/L3 cached) ----
    bf16x8 wf[3][8];
    #pragma unroll
    for (int cb = 0; cb < 3; ++cb) {
        #pragma unroll
        for (int kk = 0; kk < 8; ++kk) {
            int rowc = cb * 16 + lr;
            float4 w0 = {0.f, 0.f, 0.f, 0.f}, w1 = {0.f, 0.f, 0.f, 0.f};
            if (rowc < C_DIM) {
                const float* wp = W + rowc * K_DIM + kg * 8 + kk * 32;
                w0 = *reinterpret_cast<const float4*>(wp);
                w1 = *reinterpret_cast<const float4*>(wp + 4);
            }
            union { bf16x8 v; unsigned u[4]; } uw;
            uw.u[0] = pack_bf16(w0.x, w0.y);
            uw.u[1] = pack_bf16(w0.z, w0.w);
            uw.u[2] = pack_bf16(w1.x, w1.y);
            uw.u[3] = pack_bf16(w1.z, w1.w);
            wf[cb][kk] = uw.v;
        }
    }

    float4 bia0 = *reinterpret_cast<const float4*>(b + kg * 4);
    float4 bia1 = *reinterpret_cast<const float4*>(b + 16 + kg * 4);
    float4 bia2 = {0.f, 0.f, 0.f, 0.f};
    if (kg < 2) bia2 = *reinterpret_cast<const float4*>(b + 32 + kg * 4);

    // issue 8 global_load_lds (1KB each) for half-tile h -> buffer h&1
    // aux=2 -> CPol NT: no L2/L3 allocation for the single-use x stream.
    auto stage = [&](int h) {
        size_t tile = (size_t)(h >> 1) * 2048 + gw;
        const char* gbase = reinterpret_cast<const char*>(x)
                          + tile * 16384 + (h & 1) * 512;
        float* lbase = &shX[wave][h & 1][0][0];
        #pragma unroll
        for (int j = 0; j < 8; ++j) {
            int r = 2 * j + (lane >> 5);
            const void* gp = gbase + r * 1024 + (lane & 31) * 16;  // linear
            __builtin_amdgcn_global_load_lds(
                (const __attribute__((address_space(1))) void*)gp,
                (__attribute__((address_space(3))) void*)(lbase + j * 256),
                16, 0, 2 /* NT */);
        }
    };

    f32x4v acc0, acc1, acc2;

#define COMPUTE_HALF(KH)                                                          \
    do {                                                                          \
        const char* cX = reinterpret_cast<const char*>(&shX[wave][KH][0][0]);     \
        _Pragma("unroll")                                                         \
        for (int kt = 0; kt < 4; ++kt) {                                          \
            int k0 = kg * 32 + kt * 128;                                          \
            float4 d0 = *reinterpret_cast<const float4*>(cX + lr * 512 + k0);      \
            float4 d1 = *reinterpret_cast<const float4*>(cX + lr * 512 + k0 + 16); \
            union { bf16x8 v; unsigned u[4]; } xf;                                \
            xf.u[0] = cvt_pk(d0.x, d0.y);                                         \
            xf.u[1] = cvt_pk(d0.z, d0.w);                                         \
            xf.u[2] = cvt_pk(d1.x, d1.y);                                         \
            xf.u[3] = cvt_pk(d1.z, d1.w);                                         \
            acc0 = __builtin_amdgcn_mfma_f32_16x16x32_bf16(wf[0][KH * 4 + kt], xf.v, acc0, 0, 0, 0); \
            acc1 = __builtin_amdgcn_mfma_f32_16x16x32_bf16(wf[1][KH * 4 + kt], xf.v, acc1, 0, 0, 0); \
            acc2 = __builtin_amdgcn_mfma_f32_16x16x32_bf16(wf[2][KH * 4 + kt], xf.v, acc2, 0, 0, 0); \
        }                                                                         \
    } while (0)

    stage(0);
    stage(1);

    for (int t = 0; t < 8; ++t) {
        // ---- phase A: k-half 0 ----
        __builtin_amdgcn_sched_barrier(0);
        if (t == 0) asm volatile("s_waitcnt vmcnt(8)" ::: "memory");
        else        asm volatile("s_waitcnt vmcnt(11)" ::: "memory");
        __builtin_amdgcn_sched_barrier(0);
        acc0 = (f32x4v){0.f, 0.f, 0.f, 0.f};
        acc1 = (f32x4v){0.f, 0.f, 0.f, 0.f};
        acc2 = (f32x4v){0.f, 0.f, 0.f, 0.f};
        COMPUTE_HALF(0);
        __builtin_amdgcn_sched_barrier(0);
        if (t < 7) stage(2 * t + 2);

        // ---- phase B: k-half 1 ----
        __builtin_amdgcn_sched_barrier(0);
        if (t < 7) asm volatile("s_waitcnt vmcnt(8)" ::: "memory");
        else       asm volatile("s_waitcnt vmcnt(0)" ::: "memory");
        __builtin_amdgcn_sched_barrier(0);
        COMPUTE_HALF(1);

        // ---- epilogue: bias + tanh + bf16 store ----
        size_t row = ((size_t)t * 2048 + gw) * 16 + lr;
        unsigned* yr = ybf + row * 20;          // 40 bf16 = 20 u32 per row
        float o00 = 5.f * fast_tanh(acc0[0] + bia0.x);
        float o01 = 5.f * fast_tanh(acc0[1] + bia0.y);
        float o02 = 5.f * fast_tanh(acc0[2] + bia0.z);
        float o03 = 5.f * fast_tanh(acc0[3] + bia0.w);
        float o10 = 5.f * fast_tanh(acc1[0] + bia1.x);
        float o11 = 5.f * fast_tanh(acc1[1] + bia1.y);
        float o12 = 5.f * fast_tanh(acc1[2] + bia1.z);
        float o13 = 5.f * fast_tanh(acc1[3] + bia1.w);
        uint2 p0, p1;
        p0.x = cvt_pk(o00, o01); p0.y = cvt_pk(o02, o03);
        p1.x = cvt_pk(o10, o11); p1.y = cvt_pk(o12, o13);
        *reinterpret_cast<uint2*>(yr + kg * 2) = p0;
        *reinterpret_cast<uint2*>(yr + 8 + kg * 2) = p1;
        if (kg < 2) {
            float o20 = 5.f * fast_tanh(acc2[0] + bia2.x);
            float o21 = 5.f * fast_tanh(acc2[1] + bia2.y);
            float o22 = 5.f * fast_tanh(acc2[2] + bia2.z);
            float o23 = 5.f * fast_tanh(acc2[3] + bia2.w);
            uint2 p2;
            p2.x = cvt_pk(o20, o21); p2.y = cvt_pk(o22, o23);
            *reinterpret_cast<uint2*>(yr + 16 + kg * 2) = p2;
        }

        __builtin_amdgcn_sched_barrier(0);
        if (t < 7) stage(2 * t + 3);
    }
#undef COMPUTE_HALF
}

// ---------------- Phase 2a: per-segment 8x8 transition matrices ------------
__global__ __launch_bounds__(128) void k_seg(
    const unsigned* __restrict__ ybf, float* __restrict__ segv, float* __restrict__ segl)
{
    int tid = blockIdx.x * 128 + threadIdx.x;   // 32768 total
    int n = tid & 127;
    int s = tid >> 7;

    float P[8][8];
    #pragma unroll
    for (int j = 0; j < 8; ++j)
        #pragma unroll
        for (int c = 0; c < 8; ++c) P[j][c] = (j == c) ? 1.f : 0.f;

    for (int st = 0; st < SEGLEN; ++st) {
        int t = s * SEGLEN + st;
        const unsigned* yr = ybf + ((size_t)t * N_DIM + n) * 20;
        float e[40];
        #pragma unroll
        for (int i = 0; i < 5; ++i) {
            uint4 w = reinterpret_cast<const uint4*>(yr)[i];
            e[i * 8 + 0] = __expf(bf_lo(w.x));
            e[i * 8 + 1] = __expf(bf_hi(w.x));
            e[i * 8 + 2] = __expf(bf_lo(w.y));
            e[i * 8 + 3] = __expf(bf_hi(w.y));
            e[i * 8 + 4] = __expf(bf_lo(w.z));
            e[i * 8 + 5] = __expf(bf_hi(w.z));
            e[i * 8 + 6] = __expf(bf_lo(w.w));
            e[i * 8 + 7] = __expf(bf_hi(w.w));
        }
        #pragma unroll
        for (int c = 0; c < 8; ++c) {
            float np[8];
            #pragma unroll
            for (int j = 0; j < 4; ++j) {       // flip: all 8 sources
                float a = 0.f;
                #pragma unroll
                for (int i = 0; i < 8; ++i) a += P[i][c] * e[j * 8 + i];
                np[j] = a;
            }
            #pragma unroll
            for (int j = 0; j < 4; ++j)         // flop: 2 sources
                np[4 + j] = P[j][c] * e[32 + j] + P[4 + j][c] * e[36 + j];
            #pragma unroll
            for (int j = 0; j < 8; ++j) P[j][c] = np[j];
        }
    }
    #pragma unroll
    for (int c = 0; c < 8; ++c) {
        float sum = 0.f;
        #pragma unroll
        for (int j = 0; j < 8; ++j) sum += P[j][c];
        float inv = 1.f / sum;
        #pragma unroll
        for (int j = 0; j < 8; ++j)
            segv[(((size_t)s * 8 + c) * 8 + j) * N_DIM + n] = P[j][c] * inv;
        segl[((size_t)s * 8 + c) * N_DIM + n] = __logf(sum);
    }
}

// ---------------- Phase 2b: combine 32 segments per group ------------------
__global__ __launch_bounds__(128) void k_grp(
    const float* __restrict__ segv, const float* __restrict__ segl,
    float* __restrict__ grpv, float* __restrict__ grpl)
{
    int tid = blockIdx.x * 128 + threadIdx.x;  // 8192 total (64 blocks)
    int n = tid & 127;
    int cc = (tid >> 7) & 7;
    int g = tid >> 10;

    float u[8];
    #pragma unroll
    for (int i = 0; i < 8; ++i) u[i] = (i == cc) ? 1.f : 0.f;
    float logacc = 0.f;

    for (int s = g * SEGPERGRP; s < (g + 1) * SEGPERGRP; ++s) {
        float l[8];
        #pragma unroll
        for (int i = 0; i < 8; ++i) l[i] = segl[((size_t)s * 8 + i) * N_DIM + n];
        float m = l[0];
        #pragma unroll
        for (int i = 1; i < 8; ++i) m = fmaxf(m, l[i]);
        float nu[8] = {0.f, 0.f, 0.f, 0.f, 0.f, 0.f, 0.f, 0.f};
        #pragma unroll
        for (int i = 0; i < 8; ++i) {
            float wi = u[i] * __expf(l[i] - m);
            #pragma unroll
            for (int j = 0; j < 8; ++j)
                nu[j] += wi * segv[(((size_t)s * 8 + i) * 8 + j) * N_DIM + n];
        }
        float sum = 0.f;
        #pragma unroll
        for (int j = 0; j < 8; ++j) sum += nu[j];
        float inv = 1.f / sum;
        #pragma unroll
        for (int j = 0; j < 8; ++j) u[j] = nu[j] * inv;
        logacc += m + __logf(sum);
    }
    #pragma unroll
    for (int j = 0; j < 8; ++j)
        grpv[(((size_t)g * 8 + cc) * 8 + j) * N_DIM + n] = u[j];
    grpl[((size_t)g * 8 + cc) * N_DIM + n] = logacc;
}

// ---------------- Phase 2c: fold 8 groups into logZ/T ----------------------
__global__ void k_fin(const float* __restrict__ grpv, const float* __restrict__ grpl,
                      float* __restrict__ lz)
{
    int n = threadIdx.x;  // 128
    float p[8] = {0.25f, 0.25f, 0.25f, 0.25f, 0.f, 0.f, 0.f, 0.f};
    float logZ = 1.3862943611198906f;  // log(4)

    for (int g = 0; g < GRP; ++g) {
        float l[8];
        #pragma unroll
        for (int i = 0; i < 8; ++i) l[i] = grpl[((size_t)g * 8 + i) * N_DIM + n];
        float m = l[0];
        #pragma unroll
        for (int i = 1; i < 8; ++i) m = fmaxf(m, l[i]);
        float nu[8] = {0.f, 0.f, 0.f, 0.f, 0.f, 0.f, 0.f, 0.f};
        #pragma unroll
        for (int i = 0; i < 8; ++i) {
            float wi = p[i] * __expf(l[i] - m);
            #pragma unroll
            for (int j = 0; j < 8; ++j)
                nu[j] += wi * grpv[(((size_t)g * 8 + i) * 8 + j) * N_DIM + n];
        }
        float sum = 0.f;
        #pragma unroll
        for (int j = 0; j < 8; ++j) sum += nu[j];
        float inv = 1.f / sum;
        #pragma unroll
        for (int j = 0; j < 8; ++j) p[j] = nu[j] * inv;
        logZ += m + __logf(sum);
    }
    lz[n] = logZ * (1.f / (float)T_DIM);
}

// ---------------- Phase 3: out = y(bf16) - logZ[n]/T -----------------------
__global__ __launch_bounds__(256) void k_sub(const unsigned* __restrict__ ybf,
                                             const float* __restrict__ lz,
                                             float* __restrict__ out)
{
    int i = blockIdx.x * 256 + threadIdx.x;   // float4-out index; 2621440 total
    int n = (i / 10) & 127;
    float d = lz[n];
    uint2 w = *reinterpret_cast<const uint2*>(ybf + 2 * (size_t)i);
    float4 v;
    v.x = bf_lo(w.x) - d;
    v.y = bf_hi(w.x) - d;
    v.z = bf_lo(w.y) - d;
    v.w = bf_hi(w.y) - d;
    reinterpret_cast<float4*>(out)[i] = v;
}

extern "C" void kernel_launch(void* const* d_in, const int* in_sizes, int n_in,
                              void* d_out, int out_size, void* d_ws, size_t ws_size,
                              hipStream_t stream) {
    const float* x = (const float*)d_in[0];
    const float* W = (const float*)d_in[1];
    const float* b = (const float*)d_in[2];
    float* out = (float*)d_out;
    float* ws = (float*)d_ws;

    unsigned* ybf = (unsigned*)ws;     // T*N*20 u32  (20MB)
    float* segv = ws + 5242880;        // SEG*8*8*128 = 2,097,152 f32
    float* segl = ws + 7340032;        // SEG*8*128   =   262,144 f32
    float* grpv = ws + 7602176;        // GRP*8*8*128 =    65,536 f32
    float* grpl = ws + 7667712;        // GRP*8*128   =     8,192 f32
    float* lz   = ws + 7675904;        // 128 f32     (total ~30.7 MB)

    k_gemm_tanh<<<512, 256, 0, stream>>>(x, W, b, ybf);
    k_seg<<<256, 128, 0, stream>>>(ybf, segv, segl);
    k_grp<<<64, 128, 0, stream>>>(segv, segl, grpv, grpl);
    k_fin<<<1, 128, 0, stream>>>(grpv, grpl, lz);
    k_sub<<<10240, 256, 0, stream>>>(ybf, lz, out);
}